// Round 1
// baseline (2679.411 us; speedup 1.0000x reference)
//
#include <hip/hip_runtime.h>

#define F_IN 500
#define HDIM 64
#define CDIM 10

// ---------------------------------------------------------------------------
// Stage 1: in-degree histogram (self-loop handled later as +1)
// ---------------------------------------------------------------------------
__global__ void deg_count_kernel(const int* __restrict__ dst, int E,
                                 int* __restrict__ deg) {
    int e = blockIdx.x * blockDim.x + threadIdx.x;
    if (e < E) atomicAdd(&deg[dst[e]], 1);
}

// dis[i] = (deg[i]+1)^-1/2   (deg includes self-loop => always > 0)
__global__ void dis_kernel(const int* __restrict__ deg, float* __restrict__ dis,
                           int N) {
    int i = blockIdx.x * blockDim.x + threadIdx.x;
    if (i < N) dis[i] = rsqrtf((float)(deg[i] + 1));
}

// ---------------------------------------------------------------------------
// Stage 2: h1 = x @ W1  (one thread per node, 64 fp32 accumulators)
// Also fuses the layer-1 self-loop: agg1 = h1 * dis^2
// ---------------------------------------------------------------------------
__global__ void gemm1_kernel(const float* __restrict__ x,
                             const float* __restrict__ W1,
                             const float* __restrict__ dis,
                             float* __restrict__ h1,
                             float* __restrict__ agg1, int N) {
    int n = blockIdx.x * blockDim.x + threadIdx.x;
    if (n >= N) return;
    float acc[HDIM];
#pragma unroll
    for (int c = 0; c < HDIM; ++c) acc[c] = 0.f;

    // x rows are 500 floats = 2000 B => 16 B aligned; 125 float4 loads.
    const float4* xrow = reinterpret_cast<const float4*>(x + (size_t)n * F_IN);
    for (int k4 = 0; k4 < F_IN / 4; ++k4) {
        float4 xv = xrow[k4];
        const float* w = W1 + (size_t)k4 * 4 * HDIM;  // wave-uniform address
#pragma unroll
        for (int c = 0; c < HDIM; ++c) acc[c] = fmaf(xv.x, w[c], acc[c]);
#pragma unroll
        for (int c = 0; c < HDIM; ++c) acc[c] = fmaf(xv.y, w[HDIM + c], acc[c]);
#pragma unroll
        for (int c = 0; c < HDIM; ++c) acc[c] = fmaf(xv.z, w[2 * HDIM + c], acc[c]);
#pragma unroll
        for (int c = 0; c < HDIM; ++c) acc[c] = fmaf(xv.w, w[3 * HDIM + c], acc[c]);
    }

    float ds = dis[n];
    float d2 = ds * ds;
    float* h1r = h1 + (size_t)n * HDIM;
    float* a1r = agg1 + (size_t)n * HDIM;
#pragma unroll
    for (int c = 0; c < HDIM; ++c) {
        h1r[c] = acc[c];
        a1r[c] = acc[c] * d2;  // self-loop contribution; also inits agg1
    }
}

// ---------------------------------------------------------------------------
// Stage 3: scatter-add layer 1.  16 threads per edge, float4 each.
// ---------------------------------------------------------------------------
__global__ void scatter1_kernel(const int* __restrict__ src,
                                const int* __restrict__ dst,
                                const float* __restrict__ dis,
                                const float* __restrict__ h1,
                                float* __restrict__ agg1, int E) {
    long long t = (long long)blockIdx.x * blockDim.x + threadIdx.x;
    int e = (int)(t >> 4);
    if (e >= E) return;
    int part = (int)(t & 15);
    int s = src[e], d = dst[e];
    float norm = dis[s] * dis[d];
    const float4* hr = reinterpret_cast<const float4*>(h1 + (size_t)s * HDIM);
    float4 v = hr[part];
    float* outp = agg1 + (size_t)d * HDIM + part * 4;
    atomicAdd(outp + 0, v.x * norm);
    atomicAdd(outp + 1, v.y * norm);
    atomicAdd(outp + 2, v.z * norm);
    atomicAdd(outp + 3, v.w * norm);
}

// ---------------------------------------------------------------------------
// Stage 4: layer 2 dense part, fused:
//   t = relu(agg1 + b1);  h2 = t @ W2;  out = h2*dis^2 + b2  (self-loop+bias)
// ---------------------------------------------------------------------------
__global__ void layer2_kernel(const float* __restrict__ agg1,
                              const float* __restrict__ b1,
                              const float* __restrict__ W2,
                              const float* __restrict__ b2,
                              const float* __restrict__ dis,
                              float* __restrict__ h2,
                              float* __restrict__ out, int N) {
    int n = blockIdx.x * blockDim.x + threadIdx.x;
    if (n >= N) return;
    const float* ar = agg1 + (size_t)n * HDIM;
    float t[HDIM];
#pragma unroll
    for (int c = 0; c < HDIM; ++c) {
        float v = ar[c] + b1[c];
        t[c] = v > 0.f ? v : 0.f;
    }
    float ds = dis[n];
    float d2 = ds * ds;
    float* h2r = h2 + (size_t)n * CDIM;
    float* outr = out + (size_t)n * CDIM;
#pragma unroll
    for (int j = 0; j < CDIM; ++j) {
        float acc = 0.f;
#pragma unroll
        for (int c = 0; c < HDIM; ++c) acc = fmaf(t[c], W2[c * CDIM + j], acc);
        h2r[j] = acc;
        outr[j] = acc * d2 + b2[j];  // self-loop + bias init of output
    }
}

// ---------------------------------------------------------------------------
// Stage 5: scatter-add layer 2.  1 thread per edge (10 features).
// ---------------------------------------------------------------------------
__global__ void scatter2_kernel(const int* __restrict__ src,
                                const int* __restrict__ dst,
                                const float* __restrict__ dis,
                                const float* __restrict__ h2,
                                float* __restrict__ out, int E) {
    int e = blockIdx.x * blockDim.x + threadIdx.x;
    if (e >= E) return;
    int s = src[e], d = dst[e];
    float norm = dis[s] * dis[d];
    const float* hr = h2 + (size_t)s * CDIM;
    float* outr = out + (size_t)d * CDIM;
#pragma unroll
    for (int j = 0; j < CDIM; ++j) atomicAdd(outr + j, hr[j] * norm);
}

// ---------------------------------------------------------------------------
extern "C" void kernel_launch(void* const* d_in, const int* in_sizes, int n_in,
                              void* d_out, int out_size, void* d_ws,
                              size_t ws_size, hipStream_t stream) {
    const float* x  = (const float*)d_in[0];
    const int*   ei = (const int*)d_in[1];
    const float* W1 = (const float*)d_in[2];
    const float* b1 = (const float*)d_in[3];
    const float* W2 = (const float*)d_in[4];
    const float* b2 = (const float*)d_in[5];

    const int N = in_sizes[0] / F_IN;   // 100000
    const int E = in_sizes[1] / 2;      // 1600000
    const int* src = ei;
    const int* dst = ei + E;
    float* out = (float*)d_out;

    // workspace layout (52 MB total)
    char* w = (char*)d_ws;
    int*   deg  = (int*)w;    w += (size_t)N * 4;
    float* dis  = (float*)w;  w += (size_t)N * 4;
    float* h1   = (float*)w;  w += (size_t)N * HDIM * 4;
    float* agg1 = (float*)w;  w += (size_t)N * HDIM * 4;
    float* h2   = h1;  // h1 dead after scatter1; reuse for h2

    hipMemsetAsync(deg, 0, (size_t)N * 4, stream);

    deg_count_kernel<<<(E + 255) / 256, 256, 0, stream>>>(dst, E, deg);
    dis_kernel<<<(N + 255) / 256, 256, 0, stream>>>(deg, dis, N);
    gemm1_kernel<<<(N + 255) / 256, 256, 0, stream>>>(x, W1, dis, h1, agg1, N);
    {
        long long nthreads = (long long)E * 16;
        int blocks = (int)((nthreads + 255) / 256);
        scatter1_kernel<<<blocks, 256, 0, stream>>>(src, dst, dis, h1, agg1, E);
    }
    layer2_kernel<<<(N + 255) / 256, 256, 0, stream>>>(agg1, b1, W2, b2, dis,
                                                       h2, out, N);
    scatter2_kernel<<<(E + 255) / 256, 256, 0, stream>>>(src, dst, dis, h2, out, E);
}

// Round 2
// 822.124 us; speedup vs baseline: 3.2591x; 3.2591x over previous
//
#include <hip/hip_runtime.h>

#define F_IN 500
#define HDIM 64
#define CDIM 10

// ---------------------------------------------------------------------------
// Stage 1: in-degree histogram (real edges only; self-loop = +1 at rsqrt)
// ---------------------------------------------------------------------------
__global__ void deg_count_kernel(const int* __restrict__ dst, int E,
                                 int* __restrict__ deg) {
    int e = blockIdx.x * blockDim.x + threadIdx.x;
    if (e < E) atomicAdd(&deg[dst[e]], 1);
}

__global__ void dis_kernel(const int* __restrict__ deg, float* __restrict__ dis,
                           int N) {
    int i = blockIdx.x * blockDim.x + threadIdx.x;
    if (i < N) dis[i] = rsqrtf((float)(deg[i] + 1));
}

// ---------------------------------------------------------------------------
// Stage 2: exclusive prefix scan of deg -> row_ptr[N+1].  Single block,
// 1024 threads, wave shfl scan + LDS cross-wave combine, serial carry.
// ---------------------------------------------------------------------------
__global__ void scan_kernel(const int* __restrict__ deg,
                            int* __restrict__ row_ptr, int N) {
    __shared__ int wsum[16];
    int carry = 0;
    const int T = 1024;
    for (int base = 0; base < N; base += T) {
        int i = base + (int)threadIdx.x;
        int v = (i < N) ? deg[i] : 0;
        int lane = threadIdx.x & 63;
        int wid = threadIdx.x >> 6;
        int x = v;  // inclusive scan within wave
#pragma unroll
        for (int off = 1; off < 64; off <<= 1) {
            int y = __shfl_up(x, off);
            if (lane >= off) x += y;
        }
        if (lane == 63) wsum[wid] = x;
        __syncthreads();
        if (threadIdx.x < 16) {
            int ws = wsum[threadIdx.x];
#pragma unroll
            for (int off = 1; off < 16; off <<= 1) {
                int y = __shfl_up(ws, off);
                if ((int)threadIdx.x >= off) ws += y;
            }
            wsum[threadIdx.x] = ws;  // inclusive wave totals
        }
        __syncthreads();
        int wave_prefix = (wid > 0) ? wsum[wid - 1] : 0;
        int excl = carry + wave_prefix + (x - v);
        if (i < N) row_ptr[i] = excl;
        int chunk_total = wsum[15];
        __syncthreads();  // protect wsum before next iteration overwrites
        carry += chunk_total;
    }
    if (threadIdx.x == 0) row_ptr[N] = carry;
}

// ---------------------------------------------------------------------------
// Stage 3: CSR fill.  cursor[] must be zeroed.  Within-node order is
// nondeterministic (fp sum order only; tolerance covers it).
// ---------------------------------------------------------------------------
__global__ void csr_fill_kernel(const int* __restrict__ src,
                                const int* __restrict__ dst,
                                const int* __restrict__ row_ptr,
                                int* __restrict__ cursor,
                                int* __restrict__ csr_src, int E) {
    int e = blockIdx.x * blockDim.x + threadIdx.x;
    if (e >= E) return;
    int d = dst[e];
    int pos = atomicAdd(&cursor[d], 1);
    csr_src[row_ptr[d] + pos] = src[e];
}

// ---------------------------------------------------------------------------
// Stage 4: h1 = x @ W1  (one thread per node, 64 fp32 accumulators)
// ---------------------------------------------------------------------------
__global__ void gemm1_kernel(const float* __restrict__ x,
                             const float* __restrict__ W1,
                             float* __restrict__ h1, int N) {
    int n = blockIdx.x * blockDim.x + threadIdx.x;
    if (n >= N) return;
    float acc[HDIM];
#pragma unroll
    for (int c = 0; c < HDIM; ++c) acc[c] = 0.f;

    const float4* xrow = reinterpret_cast<const float4*>(x + (size_t)n * F_IN);
    for (int k4 = 0; k4 < F_IN / 4; ++k4) {
        float4 xv = xrow[k4];
        const float* w = W1 + (size_t)k4 * 4 * HDIM;  // wave-uniform -> s_load
#pragma unroll
        for (int c = 0; c < HDIM; ++c) acc[c] = fmaf(xv.x, w[c], acc[c]);
#pragma unroll
        for (int c = 0; c < HDIM; ++c) acc[c] = fmaf(xv.y, w[HDIM + c], acc[c]);
#pragma unroll
        for (int c = 0; c < HDIM; ++c) acc[c] = fmaf(xv.z, w[2 * HDIM + c], acc[c]);
#pragma unroll
        for (int c = 0; c < HDIM; ++c) acc[c] = fmaf(xv.w, w[3 * HDIM + c], acc[c]);
    }
    float* h1r = h1 + (size_t)n * HDIM;
#pragma unroll
    for (int c = 0; c < HDIM; ++c) h1r[c] = acc[c];
}

// ---------------------------------------------------------------------------
// Stage 5: gather layer 1.  One wave per node, lane = feature.
// agg1[n][f] = h1[n][f]*dis[n]^2 + sum_{s in in(n)} h1[s][f]*dis[s]*dis[n]
// ---------------------------------------------------------------------------
__global__ void gather1_kernel(const int* __restrict__ row_ptr,
                               const int* __restrict__ csr_src,
                               const float* __restrict__ dis,
                               const float* __restrict__ h1,
                               float* __restrict__ agg1, int N) {
    int nid = blockIdx.x * 4 + (threadIdx.x >> 6);
    if (nid >= N) return;
    int node = __builtin_amdgcn_readfirstlane(nid);  // force SGPR addressing
    int lane = threadIdx.x & 63;
    int beg = row_ptr[node];
    int end = row_ptr[node + 1];
    float dd = dis[node];
    float acc = h1[(size_t)node * HDIM + lane] * dd * dd;  // self-loop
    int p = beg;
    for (; p + 1 < end; p += 2) {  // 2-edge unroll for ILP
        int s0 = csr_src[p];
        int s1 = csr_src[p + 1];
        float n0 = dis[s0] * dd;
        float n1 = dis[s1] * dd;
        acc = fmaf(h1[(size_t)s0 * HDIM + lane], n0, acc);
        acc = fmaf(h1[(size_t)s1 * HDIM + lane], n1, acc);
    }
    if (p < end) {
        int s0 = csr_src[p];
        acc = fmaf(h1[(size_t)s0 * HDIM + lane], dis[s0] * dd, acc);
    }
    agg1[(size_t)node * HDIM + lane] = acc;
}

// ---------------------------------------------------------------------------
// Stage 6: layer 2 dense part: t = relu(agg1 + b1); h2 = t @ W2
// ---------------------------------------------------------------------------
__global__ void layer2_kernel(const float* __restrict__ agg1,
                              const float* __restrict__ b1,
                              const float* __restrict__ W2,
                              float* __restrict__ h2, int N) {
    int n = blockIdx.x * blockDim.x + threadIdx.x;
    if (n >= N) return;
    const float* ar = agg1 + (size_t)n * HDIM;
    float t[HDIM];
#pragma unroll
    for (int c = 0; c < HDIM; ++c) {
        float v = ar[c] + b1[c];
        t[c] = v > 0.f ? v : 0.f;
    }
    float* h2r = h2 + (size_t)n * CDIM;
#pragma unroll
    for (int j = 0; j < CDIM; ++j) {
        float acc = 0.f;
#pragma unroll
        for (int c = 0; c < HDIM; ++c) acc = fmaf(t[c], W2[c * CDIM + j], acc);
        h2r[j] = acc;
    }
}

// ---------------------------------------------------------------------------
// Stage 7: gather layer 2.  16 lanes per node (10 active), j = feature.
// out[n][j] = b2[j] + h2[n][j]*dis[n]^2 + sum h2[s][j]*dis[s]*dis[n]
// ---------------------------------------------------------------------------
__global__ void gather2_kernel(const int* __restrict__ row_ptr,
                               const int* __restrict__ csr_src,
                               const float* __restrict__ dis,
                               const float* __restrict__ h2,
                               const float* __restrict__ b2,
                               float* __restrict__ out, int N) {
    int t = blockIdx.x * blockDim.x + threadIdx.x;
    int node = t >> 4;
    int j = t & 15;
    if (node >= N || j >= CDIM) return;
    int beg = row_ptr[node];
    int end = row_ptr[node + 1];
    float dd = dis[node];
    float acc = h2[(size_t)node * CDIM + j] * dd * dd + b2[j];
    for (int p = beg; p < end; ++p) {
        int s = csr_src[p];
        acc = fmaf(h2[(size_t)s * CDIM + j], dis[s] * dd, acc);
    }
    out[(size_t)node * CDIM + j] = acc;
}

// ---------------------------------------------------------------------------
extern "C" void kernel_launch(void* const* d_in, const int* in_sizes, int n_in,
                              void* d_out, int out_size, void* d_ws,
                              size_t ws_size, hipStream_t stream) {
    const float* x  = (const float*)d_in[0];
    const int*   ei = (const int*)d_in[1];
    const float* W1 = (const float*)d_in[2];
    const float* b1 = (const float*)d_in[3];
    const float* W2 = (const float*)d_in[4];
    const float* b2 = (const float*)d_in[5];

    const int N = in_sizes[0] / F_IN;   // 100000
    const int E = in_sizes[1] / 2;      // 1600000
    const int* src = ei;
    const int* dst = ei + E;
    float* out = (float*)d_out;

    // workspace layout (~59 MB)
    char* w = (char*)d_ws;
    int*   deg     = (int*)w;    w += (size_t)N * 4;          // zeroed
    int*   cursor  = (int*)w;    w += (size_t)N * 4;          // zeroed
    float* dis     = (float*)w;  w += (size_t)N * 4;
    int*   row_ptr = (int*)w;    w += (size_t)(N + 4) * 4;
    int*   csr_src = (int*)w;    w += (size_t)E * 4;
    float* h1      = (float*)w;  w += (size_t)N * HDIM * 4;
    float* agg1    = (float*)w;  w += (size_t)N * HDIM * 4;
    float* h2      = h1;  // h1 dead after gather1; reuse (4 MB < 25.6 MB)

    hipMemsetAsync(deg, 0, (size_t)N * 2 * 4, stream);  // deg + cursor

    deg_count_kernel<<<(E + 255) / 256, 256, 0, stream>>>(dst, E, deg);
    dis_kernel<<<(N + 255) / 256, 256, 0, stream>>>(deg, dis, N);
    scan_kernel<<<1, 1024, 0, stream>>>(deg, row_ptr, N);
    csr_fill_kernel<<<(E + 255) / 256, 256, 0, stream>>>(src, dst, row_ptr,
                                                         cursor, csr_src, E);
    gemm1_kernel<<<(N + 255) / 256, 256, 0, stream>>>(x, W1, h1, N);
    gather1_kernel<<<(N + 3) / 4, 256, 0, stream>>>(row_ptr, csr_src, dis, h1,
                                                    agg1, N);
    layer2_kernel<<<(N + 255) / 256, 256, 0, stream>>>(agg1, b1, W2, h2, N);
    {
        long long nthreads = (long long)N * 16;
        int blocks = (int)((nthreads + 255) / 256);
        gather2_kernel<<<blocks, 256, 0, stream>>>(row_ptr, csr_src, dis, h2,
                                                   b2, out, N);
    }
}

// Round 3
// 651.112 us; speedup vs baseline: 4.1151x; 1.2626x over previous
//
#include <hip/hip_runtime.h>

#define F_IN 500
#define HDIM 64
#define CDIM 10

// gemm tiling
#define MT 128          // nodes per block
#define KT 20           // k-slice per stage (500 = 25 * 20)
#define XS_LD 132       // padded leading dim for xs (16B-aligned rows, bank-spread)

// ---------------------------------------------------------------------------
// Stage 1: in-degree histogram (real edges only; self-loop = +1 at rsqrt)
// ---------------------------------------------------------------------------
__global__ void deg_count_kernel(const int* __restrict__ dst, int E,
                                 int* __restrict__ deg) {
    int e = blockIdx.x * blockDim.x + threadIdx.x;
    if (e < E) atomicAdd(&deg[dst[e]], 1);
}

__global__ void dis_kernel(const int* __restrict__ deg, float* __restrict__ dis,
                           int N) {
    int i = blockIdx.x * blockDim.x + threadIdx.x;
    if (i < N) dis[i] = rsqrtf((float)(deg[i] + 1));
}

// ---------------------------------------------------------------------------
// Stage 2: hierarchical exclusive scan deg -> row_ptr[N+1]
//   A) per-block (1024 elems) local exclusive scan + block totals
//   B) single-wave scan of block totals (in place -> block offsets)
//   C) add block offset to every element
// ---------------------------------------------------------------------------
__global__ void scan_block_kernel(const int* __restrict__ deg,
                                  int* __restrict__ row_ptr,
                                  int* __restrict__ blk_sum, int Np1) {
    __shared__ int wsum[16];
    int i = blockIdx.x * 1024 + threadIdx.x;
    int v = (i < Np1 - 1) ? deg[i] : 0;  // element N (and pad) = 0
    int lane = threadIdx.x & 63;
    int wid = threadIdx.x >> 6;
    int x = v;
#pragma unroll
    for (int off = 1; off < 64; off <<= 1) {
        int y = __shfl_up(x, off);
        if (lane >= off) x += y;
    }
    if (lane == 63) wsum[wid] = x;
    __syncthreads();
    if (threadIdx.x < 16) {
        int ws = wsum[threadIdx.x];
#pragma unroll
        for (int off = 1; off < 16; off <<= 1) {
            int y = __shfl_up(ws, off);
            if ((int)threadIdx.x >= off) ws += y;
        }
        wsum[threadIdx.x] = ws;
    }
    __syncthreads();
    int wp = (wid > 0) ? wsum[wid - 1] : 0;
    if (i < Np1) row_ptr[i] = wp + x - v;
    if (threadIdx.x == 1023) blk_sum[blockIdx.x] = wp + x;
}

__global__ void scan_top_kernel(int* __restrict__ blk_sum, int nb) {
    int carry = 0;
    for (int base = 0; base < nb; base += 64) {
        int i = base + (int)threadIdx.x;
        int v = (i < nb) ? blk_sum[i] : 0;
        int x = v;
#pragma unroll
        for (int off = 1; off < 64; off <<= 1) {
            int y = __shfl_up(x, off);
            if ((int)threadIdx.x >= off) x += y;
        }
        if (i < nb) blk_sum[i] = carry + x - v;
        carry += __shfl(x, 63);
    }
}

__global__ void scan_add_kernel(int* __restrict__ row_ptr,
                                const int* __restrict__ blk_sum, int Np1) {
    int i = blockIdx.x * blockDim.x + threadIdx.x;
    if (i < Np1) row_ptr[i] += blk_sum[i >> 10];
}

// ---------------------------------------------------------------------------
// Stage 3: CSR fill (within-node order nondeterministic; fp tolerance covers)
// ---------------------------------------------------------------------------
__global__ void csr_fill_kernel(const int* __restrict__ src,
                                const int* __restrict__ dst,
                                const int* __restrict__ row_ptr,
                                int* __restrict__ cursor,
                                int* __restrict__ csr_src, int E) {
    int e = blockIdx.x * blockDim.x + threadIdx.x;
    if (e >= E) return;
    int d = dst[e];
    int pos = atomicAdd(&cursor[d], 1);
    csr_src[row_ptr[d] + pos] = src[e];
}

// ---------------------------------------------------------------------------
// Stage 4: h1 = x @ W1 — tiled LDS GEMM.
// Block = 256 threads computes MT(128) x HDIM(64) tile; thread = 8 nodes x 4
// feats in registers. xs stored k-major (transposed) so compute reads are
// float4; XS_LD=132 keeps rows 16B-aligned and spreads banks.
// ---------------------------------------------------------------------------
__global__ __launch_bounds__(256) void gemm1_kernel(
        const float* __restrict__ x, const float* __restrict__ W1,
        float* __restrict__ h1, int N) {
    __shared__ float xs[KT * XS_LD];   // 10.56 KB
    __shared__ float ws[KT * HDIM];    // 5.12 KB
    const int t = threadIdx.x;
    const int m0 = blockIdx.x * MT;
    const int tx = t & 15;   // feature group: feats 4*tx .. 4*tx+3
    const int ty = t >> 4;   // node group:   nodes 8*ty .. 8*ty+7
    float acc[8][4];
#pragma unroll
    for (int i = 0; i < 8; ++i)
#pragma unroll
        for (int j = 0; j < 4; ++j) acc[i][j] = 0.f;

    for (int k0 = 0; k0 < F_IN; k0 += KT) {
        __syncthreads();  // protect LDS from previous iteration's readers
        // stage x-tile: 128 rows x 5 float4 (20 floats), transposed into xs
        for (int i = t; i < MT * (KT / 4); i += 256) {
            int row = i / 5;
            int c4 = i - row * 5;
            int gn = m0 + row;
            float4 v = make_float4(0.f, 0.f, 0.f, 0.f);
            if (gn < N)
                v = *reinterpret_cast<const float4*>(
                        x + (size_t)gn * F_IN + k0 + c4 * 4);
            int kk = c4 * 4;
            xs[(kk + 0) * XS_LD + row] = v.x;
            xs[(kk + 1) * XS_LD + row] = v.y;
            xs[(kk + 2) * XS_LD + row] = v.z;
            xs[(kk + 3) * XS_LD + row] = v.w;
        }
        // stage W-tile: KT x 64 floats = 320 float4, contiguous
        for (int i = t; i < (KT * HDIM) / 4; i += 256) {
            float4 v = *reinterpret_cast<const float4*>(
                    W1 + (size_t)k0 * HDIM + i * 4);
            *reinterpret_cast<float4*>(ws + i * 4) = v;
        }
        __syncthreads();
#pragma unroll 4
        for (int k = 0; k < KT; ++k) {
            float4 xa = *reinterpret_cast<const float4*>(xs + k * XS_LD + ty * 8);
            float4 xb = *reinterpret_cast<const float4*>(xs + k * XS_LD + ty * 8 + 4);
            float4 wv = *reinterpret_cast<const float4*>(ws + k * HDIM + tx * 4);
            float xv[8] = {xa.x, xa.y, xa.z, xa.w, xb.x, xb.y, xb.z, xb.w};
            float wf[4] = {wv.x, wv.y, wv.z, wv.w};
#pragma unroll
            for (int i = 0; i < 8; ++i)
#pragma unroll
                for (int j = 0; j < 4; ++j)
                    acc[i][j] = fmaf(xv[i], wf[j], acc[i][j]);
        }
    }
    // write out: float4 per node row
#pragma unroll
    for (int i = 0; i < 8; ++i) {
        int gn = m0 + ty * 8 + i;
        if (gn < N)
            *reinterpret_cast<float4*>(h1 + (size_t)gn * HDIM + tx * 4) =
                make_float4(acc[i][0], acc[i][1], acc[i][2], acc[i][3]);
    }
}

// ---------------------------------------------------------------------------
// Stage 5: gather layer 1.  One wave per node, lane = feature.
// ---------------------------------------------------------------------------
__global__ void gather1_kernel(const int* __restrict__ row_ptr,
                               const int* __restrict__ csr_src,
                               const float* __restrict__ dis,
                               const float* __restrict__ h1,
                               float* __restrict__ agg1, int N) {
    int nid = blockIdx.x * 4 + (threadIdx.x >> 6);
    if (nid >= N) return;
    int node = __builtin_amdgcn_readfirstlane(nid);  // force SGPR addressing
    int lane = threadIdx.x & 63;
    int beg = row_ptr[node];
    int end = row_ptr[node + 1];
    float dd = dis[node];
    float acc = h1[(size_t)node * HDIM + lane] * dd * dd;  // self-loop
    int p = beg;
    for (; p + 1 < end; p += 2) {
        int s0 = csr_src[p];
        int s1 = csr_src[p + 1];
        float n0 = dis[s0] * dd;
        float n1 = dis[s1] * dd;
        acc = fmaf(h1[(size_t)s0 * HDIM + lane], n0, acc);
        acc = fmaf(h1[(size_t)s1 * HDIM + lane], n1, acc);
    }
    if (p < end) {
        int s0 = csr_src[p];
        acc = fmaf(h1[(size_t)s0 * HDIM + lane], dis[s0] * dd, acc);
    }
    agg1[(size_t)node * HDIM + lane] = acc;
}

// ---------------------------------------------------------------------------
// Stage 6: layer 2 dense: t = relu(agg1 + b1); h2 = t @ W2
// ---------------------------------------------------------------------------
__global__ void layer2_kernel(const float* __restrict__ agg1,
                              const float* __restrict__ b1,
                              const float* __restrict__ W2,
                              float* __restrict__ h2, int N) {
    int n = blockIdx.x * blockDim.x + threadIdx.x;
    if (n >= N) return;
    const float* ar = agg1 + (size_t)n * HDIM;
    float t[HDIM];
#pragma unroll
    for (int c = 0; c < HDIM; ++c) {
        float v = ar[c] + b1[c];
        t[c] = v > 0.f ? v : 0.f;
    }
    float* h2r = h2 + (size_t)n * CDIM;
#pragma unroll
    for (int j = 0; j < CDIM; ++j) {
        float acc = 0.f;
#pragma unroll
        for (int c = 0; c < HDIM; ++c) acc = fmaf(t[c], W2[c * CDIM + j], acc);
        h2r[j] = acc;
    }
}

// ---------------------------------------------------------------------------
// Stage 7: gather layer 2.  16 lanes per node (10 active), j = feature.
// ---------------------------------------------------------------------------
__global__ void gather2_kernel(const int* __restrict__ row_ptr,
                               const int* __restrict__ csr_src,
                               const float* __restrict__ dis,
                               const float* __restrict__ h2,
                               const float* __restrict__ b2,
                               float* __restrict__ out, int N) {
    int t = blockIdx.x * blockDim.x + threadIdx.x;
    int node = t >> 4;
    int j = t & 15;
    if (node >= N || j >= CDIM) return;
    int beg = row_ptr[node];
    int end = row_ptr[node + 1];
    float dd = dis[node];
    float acc = h2[(size_t)node * CDIM + j] * dd * dd + b2[j];
    for (int p = beg; p < end; ++p) {
        int s = csr_src[p];
        acc = fmaf(h2[(size_t)s * CDIM + j], dis[s] * dd, acc);
    }
    out[(size_t)node * CDIM + j] = acc;
}

// ---------------------------------------------------------------------------
extern "C" void kernel_launch(void* const* d_in, const int* in_sizes, int n_in,
                              void* d_out, int out_size, void* d_ws,
                              size_t ws_size, hipStream_t stream) {
    const float* x  = (const float*)d_in[0];
    const int*   ei = (const int*)d_in[1];
    const float* W1 = (const float*)d_in[2];
    const float* b1 = (const float*)d_in[3];
    const float* W2 = (const float*)d_in[4];
    const float* b2 = (const float*)d_in[5];

    const int N = in_sizes[0] / F_IN;   // 100000
    const int E = in_sizes[1] / 2;      // 1600000
    const int* src = ei;
    const int* dst = ei + E;
    float* out = (float*)d_out;

    const int Np1 = N + 1;
    const int nscan_blocks = (Np1 + 1023) / 1024;  // 98

    // workspace layout (~59 MB)
    char* w = (char*)d_ws;
    int*   deg     = (int*)w;    w += (size_t)N * 4;          // zeroed
    int*   cursor  = (int*)w;    w += (size_t)N * 4;          // zeroed
    float* dis     = (float*)w;  w += (size_t)N * 4;
    int*   row_ptr = (int*)w;    w += (size_t)(N + 4) * 4;
    int*   blk_sum = (int*)w;    w += (size_t)((nscan_blocks + 63) & ~63) * 4;
    int*   csr_src = (int*)w;    w += (size_t)E * 4;
    float* h1      = (float*)w;  w += (size_t)N * HDIM * 4;
    float* agg1    = (float*)w;  w += (size_t)N * HDIM * 4;
    float* h2      = h1;  // h1 dead after gather1; reuse

    hipMemsetAsync(deg, 0, (size_t)N * 2 * 4, stream);  // deg + cursor

    deg_count_kernel<<<(E + 255) / 256, 256, 0, stream>>>(dst, E, deg);
    dis_kernel<<<(N + 255) / 256, 256, 0, stream>>>(deg, dis, N);
    scan_block_kernel<<<nscan_blocks, 1024, 0, stream>>>(deg, row_ptr, blk_sum,
                                                         Np1);
    scan_top_kernel<<<1, 64, 0, stream>>>(blk_sum, nscan_blocks);
    scan_add_kernel<<<(Np1 + 255) / 256, 256, 0, stream>>>(row_ptr, blk_sum,
                                                           Np1);
    csr_fill_kernel<<<(E + 255) / 256, 256, 0, stream>>>(src, dst, row_ptr,
                                                         cursor, csr_src, E);
    gemm1_kernel<<<(N + MT - 1) / MT, 256, 0, stream>>>(x, W1, h1, N);
    gather1_kernel<<<(N + 3) / 4, 256, 0, stream>>>(row_ptr, csr_src, dis, h1,
                                                    agg1, N);
    layer2_kernel<<<(N + 255) / 256, 256, 0, stream>>>(agg1, b1, W2, h2, N);
    {
        long long nthreads = (long long)N * 16;
        int blocks = (int)((nthreads + 255) / 256);
        gather2_kernel<<<blocks, 256, 0, stream>>>(row_ptr, csr_src, dis, h2,
                                                   b2, out, N);
    }
}